// Round 3
// baseline (736.890 us; speedup 1.0000x reference)
//
#include <hip/hip_runtime.h>
#include <stdint.h>

// Qwen3 MoE sparse block: T=4096 tokens, D=2048, E=16, F=768, top-2.
// R5: 256-slot tiles (mixed 256/128) for expertA (256x32) and expertB
//     (256x64) -> halves gate/up/down re-stage demand (~430->215 MB);
//     bijective XCD swizzle groups a tile's f/d-blocks on one XCD (A/H
//     L2 reuse); wave-aggregated scatter atomics. Simple m97 schedule
//     (R3 vs R4 A/B proved schedule depth is not the limiter).

#define NTOK 4096
#define DIM  2048
#define NEXP 16
#define FDIM 768
#define BK   32

// shared control layout (int offsets into d_ws)
#define WS_CNT     0       // cnt[e] at e*16
#define WS_CUR     256
#define WS_NTILES  512
#define WS_TILE_E  576     // up to 144
#define WS_TILE_B  736
#define WS_TILE_R  896     // rows per tile (new path, up to 80)
#define WS_TOKE    1024    // int[8192]
#define WS_TOKW    9216    // float[8192]
#define WS_SLOTT   17408   // int[<=10240]
#define SLOTW_NEW  27648   // float[10240]
#define SLOTW_OLD  26624   // float[9216]  (R1 layout, proven to fit)
#define WS_TOKSLOT 40960   // int[8192]: token -> slot (for combine)
#define MAX_TILES  144

// new-path geometry
#define TMN 256           // slot rows per tile (full tile)
#define TNA 32            // expertA f tile
#define TNB 64            // expertB d tile
#define MAX_SLOTS_N 10240
#define MAX_TILES_N 80
// fallback geometry (R1)
#define TMO 64
#define MAX_SLOTS_O 9216

// new-path byte layout in ws
#define B_XBF  262144ull
#define B_H    (B_XBF + (size_t)NTOK*DIM*2)            // 17,039,360
#define B_GBF  (B_H + (size_t)MAX_SLOTS_N*FDIM*2)      // 32,768,000
#define B_UBF  (B_GBF + (size_t)NEXP*FDIM*DIM*2)
#define B_DBF  (B_UBF + (size_t)NEXP*FDIM*DIM*2)
#define WS_NEED (B_DBF + (size_t)NEXP*FDIM*DIM*2)      // ~183.8 MB
// O_slots fp32 [MAX_SLOTS_N][DIM] = 83.9MB aliases gbf+ubf (100.6MB):
// expertA (reads gbf/ubf) completes before expertB writes O (same stream);
// next iteration's cvtw_k rewrites gbf/ubf before expertA reads again.
#define B_OSL  B_GBF
#define B_HOLD 143360ull                               // fallback H (R1, proven)

typedef __attribute__((ext_vector_type(8))) short short8;
typedef __attribute__((ext_vector_type(4))) float f32x4;

__device__ __forceinline__ unsigned short f2bf(float f) {
    unsigned u = __float_as_uint(f);
    return (unsigned short)((u + 0x7FFFu + ((u >> 16) & 1u)) >> 16);  // RNE
}

__device__ __forceinline__ short8 cvt8(float4 v0, float4 v1) {
    short8 s;
    s[0] = (short)f2bf(v0.x); s[1] = (short)f2bf(v0.y);
    s[2] = (short)f2bf(v0.z); s[3] = (short)f2bf(v0.w);
    s[4] = (short)f2bf(v1.x); s[5] = (short)f2bf(v1.y);
    s[6] = (short)f2bf(v1.z); s[7] = (short)f2bf(v1.w);
    return s;
}

__device__ __forceinline__ void gl_lds16(const void* g, void* l) {
    __builtin_amdgcn_global_load_lds(
        (const __attribute__((address_space(1))) unsigned int*)g,
        (__attribute__((address_space(3))) unsigned int*)l, 16, 0, 0);
}

// ---------------- fp32 -> bf16 weight convert (3 tensors, one launch) ----------------
__global__ __launch_bounds__(256) void cvtw_k(
    const float* __restrict__ g, const float* __restrict__ u, const float* __restrict__ d,
    unsigned short* __restrict__ go, unsigned short* __restrict__ uo,
    unsigned short* __restrict__ dd, int n8)
{
    int i = blockIdx.x * 256 + threadIdx.x;
    if (i >= n8) return;
    const float* s;
    unsigned short* o;
    if (blockIdx.y == 0)      { s = g; o = go; }
    else if (blockIdx.y == 1) { s = u; o = uo; }
    else                      { s = d; o = dd; }
    const float4* p = (const float4*)(s + (size_t)i * 8);
    *(short8*)(o + (size_t)i * 8) = cvt8(p[0], p[1]);
}

// ---------------- router: logits (fp32) + top2 + histogram + x->bf16 ----------------
__global__ __launch_bounds__(256) void router_k(
    const float* __restrict__ x, const float* __restrict__ rw,
    float* __restrict__ logits_out, int* __restrict__ wsi, float* __restrict__ wsf,
    unsigned short* __restrict__ xbf)
{
    int wid = threadIdx.x >> 6, lane = threadIdx.x & 63;
    int t = blockIdx.x * 4 + wid;
    const float* xr = x + (size_t)t * DIM;

    float acc[NEXP];
#pragma unroll
    for (int e = 0; e < NEXP; e++) acc[e] = 0.f;
    for (int i = 0; i < DIM / 64; i++) {
        float xv = xr[i * 64 + lane];
        if (xbf) xbf[(size_t)t * DIM + i * 64 + lane] = f2bf(xv);
#pragma unroll
        for (int e = 0; e < NEXP; e++) acc[e] += xv * rw[e * DIM + i * 64 + lane];
    }
#pragma unroll
    for (int e = 0; e < NEXP; e++) {
        float v = acc[e];
        for (int off = 32; off; off >>= 1) v += __shfl_down(v, off);
        acc[e] = v;
    }
    if (lane == 0) {
#pragma unroll
        for (int e = 0; e < NEXP; e++) logits_out[t * NEXP + e] = acc[e];
        int i0 = 0; float m0 = acc[0];
#pragma unroll
        for (int e = 1; e < NEXP; e++) if (acc[e] > m0) { m0 = acc[e]; i0 = e; }
        int i1 = -1; float m1 = -3.4e38f;
#pragma unroll
        for (int e = 0; e < NEXP; e++) if (e != i0 && acc[e] > m1) { m1 = acc[e]; i1 = e; }
        float w0 = 1.f / (1.f + __expf(m1 - m0));
        wsi[WS_TOKE + t * 2 + 0] = i0;
        wsi[WS_TOKE + t * 2 + 1] = i1;
        wsf[WS_TOKW + t * 2 + 0] = w0;
        wsf[WS_TOKW + t * 2 + 1] = 1.f - w0;
        atomicAdd(&wsi[WS_CNT + i0 * 16], 1);
        atomicAdd(&wsi[WS_CNT + i1 * 16], 1);
    }
}

// ---------------- scan: padded offsets + tile map + slot init ----------------
// mode 1: new path - pad per expert to 128, emit 256-row tile pairs + one
//         128-row remainder tile. mode 0: fallback fixed TMO tiles.
__global__ void scan_k(int* __restrict__ wsi, float* __restrict__ wsf,
                       int mode, int slotw, int max_slots)
{
    if (threadIdx.x == 0) {
        int total = 0, tiles = 0;
        for (int e = 0; e < NEXP; e++) {
            int c = wsi[WS_CNT + e * 16];
            wsi[WS_CNT + e * 16] = total;
            if (mode == 1) {
                int n128 = (c + 127) >> 7;
                int j = 0;
                for (; j + 2 <= n128; j += 2) {
                    wsi[WS_TILE_E + tiles] = e;
                    wsi[WS_TILE_B + tiles] = total + j * 128;
                    wsi[WS_TILE_R + tiles] = 256;
                    tiles++;
                }
                if (j < n128) {
                    wsi[WS_TILE_E + tiles] = e;
                    wsi[WS_TILE_B + tiles] = total + j * 128;
                    wsi[WS_TILE_R + tiles] = 128;
                    tiles++;
                }
                total += n128 * 128;
            } else {
                int nt = (c + TMO - 1) / TMO;
                for (int j = 0; j < nt; j++) {
                    wsi[WS_TILE_E + tiles] = e;
                    wsi[WS_TILE_B + tiles] = total + j * TMO;
                    tiles++;
                }
                total += nt * TMO;
            }
        }
        wsi[WS_NTILES] = tiles;
    }
    for (int s = threadIdx.x; s < max_slots; s += blockDim.x) {
        wsi[WS_SLOTT + s] = 0;
        wsf[slotw + s] = 0.f;
    }
}

// ---------------- scatter: token -> slot (wave-aggregated atomics) ----------------
__global__ __launch_bounds__(256) void scatter_k(int* __restrict__ wsi,
                                                 float* __restrict__ wsf, int slotw)
{
    int t = blockIdx.x * blockDim.x + threadIdx.x;   // grid exactly covers NTOK
    int lane = threadIdx.x & 63;
#pragma unroll
    for (int k = 0; k < 2; k++) {
        int e = wsi[WS_TOKE + t * 2 + k];
        float w = wsf[WS_TOKW + t * 2 + k];
        int pos = 0;
        for (int x = 0; x < NEXP; x++) {
            unsigned long long mask = __ballot(e == x);
            if (e == x) {
                int leader = __ffsll((long long)mask) - 1;
                int rank = __popcll(mask & ((1ull << lane) - 1ull));
                int base = 0;
                if (lane == leader) base = atomicAdd(&wsi[WS_CUR + x * 16], __popcll(mask));
                base = __shfl(base, leader);
                pos = base + rank;
            }
        }
        int s = wsi[WS_CNT + e * 16] + pos;
        wsi[WS_SLOTT + s] = t;
        wsf[slotw + s] = w;
        wsi[WS_TOKSLOT + t * 2 + k] = s;
    }
}

// ================= NEW PATH (bf16, gl_lds, 256-row tiles) =================

// expertA: H = silu(X gate^T) * (X up^T) * w   [256 x 32 tile, 4 waves stack M]
__global__ __launch_bounds__(256) void expertA_k(
    const unsigned short* __restrict__ xbf,
    const unsigned short* __restrict__ gbf,
    const unsigned short* __restrict__ ubf,
    const int* __restrict__ wsi, const float* __restrict__ wsf,
    unsigned short* __restrict__ H)
{
    __shared__ union {
        struct {
            unsigned short A[TMN * BK];   // 16 KB
            unsigned short G[TNA * BK];   //  2 KB
            unsigned short U[TNA * BK];   //  2 KB
        } st;
        unsigned short Hs[TMN][TNA + 8];  // 20 KB (epilogue only, aliased)
    } sh;
    __shared__ int   Ts[TMN];
    __shared__ float Wl[TMN];

    // bijective XCD swizzle: all 24 f-blocks of a tile land on one XCD
    int lin  = blockIdx.y * 24 + blockIdx.x;
    int q    = (24 * MAX_TILES_N) >> 3;          // 240
    int work = (lin & 7) * q + (lin >> 3);
    int tile = work / 24;
    int f0   = (work % 24) * TNA;

    if (tile >= wsi[WS_NTILES]) return;
    int e     = wsi[WS_TILE_E + tile];
    int slot0 = wsi[WS_TILE_B + tile];
    int rows  = wsi[WS_TILE_R + tile];
    int tid   = threadIdx.x;

    {   // clamp: 128-row tiles may index past the slot arrays
        int s = slot0 + tid;
        int ok = (s < MAX_SLOTS_N);
        Ts[tid] = ok ? wsi[WS_SLOTT + s] : 0;
        Wl[tid] = ok ? wsf[SLOTW_NEW + s] : 0.f;
    }
    __syncthreads();

    int seg = tid & 3;
    // A: 4 gl_lds rounds; round j covers rows j*64 + (tid>>2)
    const unsigned short* ap[4];
#pragma unroll
    for (int j = 0; j < 4; j++)
        ap[j] = xbf + (size_t)Ts[j * 64 + (tid >> 2)] * DIM + seg * 8;
    // G/U: one round; tid<128 -> G row tid>>2, else U row (tid-128)>>2
    const unsigned short* bsrc = (tid < 128 ? gbf : ubf)
        + ((size_t)e * FDIM + f0 + ((tid & 127) >> 2)) * DIM + seg * 8;
    unsigned short* bdst = (tid < 128) ? &sh.st.G[(size_t)tid * 8]
                                       : &sh.st.U[(size_t)(tid - 128) * 8];

    int wid = tid >> 6, lane = tid & 63;
    int wm = wid * 64;
    int lr = lane & 15, lk = (lane >> 4) * 8;

    f32x4 accg[4][2], accu[4][2];
#pragma unroll
    for (int i = 0; i < 4; i++)
#pragma unroll
        for (int j = 0; j < 2; j++) { accg[i][j] = (f32x4)0.f; accu[i][j] = (f32x4)0.f; }

    for (int k0 = 0; k0 < DIM; k0 += BK) {
#pragma unroll
        for (int j = 0; j < 4; j++)
            gl_lds16(ap[j] + k0, &sh.st.A[(size_t)j * 2048 + (size_t)tid * 8]);
        gl_lds16(bsrc + k0, bdst);
        __syncthreads();

        short8 a[4], g[2], u[2];
#pragma unroll
        for (int mi = 0; mi < 4; mi++)
            a[mi] = *(const short8*)&sh.st.A[(wm + mi * 16 + lr) * BK + lk];
#pragma unroll
        for (int nj = 0; nj < 2; nj++) {
            g[nj] = *(const short8*)&sh.st.G[(nj * 16 + lr) * BK + lk];
            u[nj] = *(const short8*)&sh.st.U[(nj * 16 + lr) * BK + lk];
        }
#pragma unroll
        for (int mi = 0; mi < 4; mi++)
#pragma unroll
            for (int nj = 0; nj < 2; nj++) {
                accg[mi][nj] = __builtin_amdgcn_mfma_f32_16x16x32_bf16(a[mi], g[nj], accg[mi][nj], 0, 0, 0);
                accu[mi][nj] = __builtin_amdgcn_mfma_f32_16x16x32_bf16(a[mi], u[nj], accu[mi][nj], 0, 0, 0);
            }
        __syncthreads();
    }

    // epilogue: h = silu(g)*u*w -> Hs (bf16); Hs aliases staging (safe after barrier)
#pragma unroll
    for (int mi = 0; mi < 4; mi++)
#pragma unroll
        for (int nj = 0; nj < 2; nj++)
#pragma unroll
            for (int r = 0; r < 4; r++) {
                int m = wm + mi * 16 + (lane >> 4) * 4 + r;
                int n = nj * 16 + lr;
                float g = accg[mi][nj][r];
                float u = accu[mi][nj][r];
                float sg = g / (1.f + __expf(-g));
                sh.Hs[m][n] = f2bf(sg * u * Wl[m]);
            }
    __syncthreads();

    // coalesced store: one row per thread, 32 bf16 (skip garbage half of 128-row tiles)
    if (tid < rows) {
        unsigned short* dst = H + (size_t)(slot0 + tid) * FDIM + f0;
#pragma unroll
        for (int c = 0; c < 4; c++)
            *(short8*)(dst + c * 8) = *(const short8*)&sh.Hs[tid][c * 8];
    }
}

// expertB: O[slot] = H @ down^T  [256 x 64 tile, plain slot-major stores]
__global__ __launch_bounds__(256) void expertB_k(
    const unsigned short* __restrict__ H, const unsigned short* __restrict__ dbf,
    const int* __restrict__ wsi, float* __restrict__ O)
{
    __shared__ unsigned short As[TMN * BK];   // 16 KB
    __shared__ unsigned short Bs[TNB * BK];   //  4 KB

    int lin  = blockIdx.y * 32 + blockIdx.x;
    int q    = (32 * MAX_TILES_N) >> 3;          // 320
    int work = (lin & 7) * q + (lin >> 3);
    int tile = work >> 5;
    int d0   = (work & 31) * TNB;

    if (tile >= wsi[WS_NTILES]) return;
    int e     = wsi[WS_TILE_E + tile];
    int slot0 = wsi[WS_TILE_B + tile];
    int rows  = wsi[WS_TILE_R + tile];
    int tid   = threadIdx.x;
    int seg   = tid & 3;

    // H rows beyond the slot array (128-row tiles) read into the weight
    // region of ws - valid memory, result masked at store.
    const unsigned short* ap = H + (size_t)(slot0 + (tid >> 2)) * FDIM + seg * 8;
    const unsigned short* bp = dbf + ((size_t)e * DIM + d0 + (tid >> 2)) * FDIM + seg * 8;

    int wid = tid >> 6, lane = tid & 63;
    int wm = wid * 64;
    int lr = lane & 15, lk = (lane >> 4) * 8;

    f32x4 acc[4][4];
#pragma unroll
    for (int i = 0; i < 4; i++)
#pragma unroll
        for (int j = 0; j < 4; j++) acc[i][j] = (f32x4)0.f;

    for (int k0 = 0; k0 < FDIM; k0 += BK) {
#pragma unroll
        for (int j = 0; j < 4; j++)
            gl_lds16(ap + (size_t)j * 64 * FDIM + k0, &As[(size_t)j * 2048 + (size_t)tid * 8]);
        gl_lds16(bp + k0, &Bs[(size_t)tid * 8]);
        __syncthreads();

        short8 a[4], b[4];
#pragma unroll
        for (int i = 0; i < 4; i++) {
            a[i] = *(const short8*)&As[(wm + i * 16 + lr) * BK + lk];
            b[i] = *(const short8*)&Bs[(i * 16 + lr) * BK + lk];
        }
#pragma unroll
        for (int mi = 0; mi < 4; mi++)
#pragma unroll
            for (int nj = 0; nj < 4; nj++)
                acc[mi][nj] = __builtin_amdgcn_mfma_f32_16x16x32_bf16(a[mi], b[nj], acc[mi][nj], 0, 0, 0);
        __syncthreads();
    }

    // slot-major store (no atomics); mask garbage half of 128-row tiles
#pragma unroll
    for (int mi = 0; mi < 4; mi++)
#pragma unroll
        for (int nj = 0; nj < 4; nj++)
#pragma unroll
            for (int r = 0; r < 4; r++) {
                int m = wm + mi * 16 + (lane >> 4) * 4 + r;
                if (m < rows) {
                    int n = d0 + nj * 16 + lr;
                    O[(size_t)(slot0 + m) * DIM + n] = acc[mi][nj][r];
                }
            }
}

// combine: out[t] = O[slot0(t)] + O[slot1(t)]  (streaming, float4)
__global__ __launch_bounds__(256) void combine_k(
    const float* __restrict__ O, const int* __restrict__ wsi, float* __restrict__ out)
{
    int i = blockIdx.x * 256 + threadIdx.x;      // over NTOK*DIM/4 float4s
    int t = i >> 9, c = i & 511;                 // DIM/4 = 512
    int s0 = wsi[WS_TOKSLOT + t * 2 + 0];
    int s1 = wsi[WS_TOKSLOT + t * 2 + 1];
    float4 a = *((const float4*)(O + (size_t)s0 * DIM) + c);
    float4 b = *((const float4*)(O + (size_t)s1 * DIM) + c);
    float4 r;
    r.x = a.x + b.x; r.y = a.y + b.y; r.z = a.z + b.z; r.w = a.w + b.w;
    *((float4*)(out + (size_t)t * DIM) + c) = r;
}

// ================= FALLBACK PATH (R1 proven kernels, ~14.4 MB ws) =================

__global__ __launch_bounds__(256) void expertA64_k(
    const float* __restrict__ x, const float* __restrict__ gw, const float* __restrict__ uw,
    const int* __restrict__ wsi, const float* __restrict__ wsf,
    unsigned short* __restrict__ H)
{
    __shared__ unsigned short As[TMO][40];
    __shared__ unsigned short Bg[TMO][40];
    __shared__ unsigned short Bu[TMO][40];
    __shared__ unsigned short Hs[TMO][72];
    __shared__ int   Ts[TMO];
    __shared__ float Wl[TMO];

    int tile = blockIdx.y;
    if (tile >= wsi[WS_NTILES]) return;
    int e     = wsi[WS_TILE_E + tile];
    int slot0 = wsi[WS_TILE_B + tile];
    int f0    = blockIdx.x * 64;
    int tid   = threadIdx.x;

    if (tid < TMO) {
        Ts[tid] = wsi[WS_SLOTT + slot0 + tid];
        Wl[tid] = wsf[SLOTW_OLD + slot0 + tid];
    }
    __syncthreads();

    int row = tid >> 2, seg = tid & 3;
    const float* aRow = x  + (size_t)Ts[row] * DIM + seg * 8;
    const float* gRow = gw + ((size_t)e * FDIM + f0 + row) * DIM + seg * 8;
    const float* uRow = uw + ((size_t)e * FDIM + f0 + row) * DIM + seg * 8;

    int wid = tid >> 6, lane = tid & 63;
    int wm = (wid >> 1) * 32, wn = (wid & 1) * 32;
    int lr = lane & 15, lk = (lane >> 4) * 8;

    f32x4 accg[2][2], accu[2][2];
#pragma unroll
    for (int i = 0; i < 2; i++)
#pragma unroll
        for (int j = 0; j < 2; j++) { accg[i][j] = (f32x4)0.f; accu[i][j] = (f32x4)0.f; }

    for (int k0 = 0; k0 < DIM; k0 += BK) {
        { const float4* p = (const float4*)(aRow + k0); *(short8*)&As[row][seg * 8] = cvt8(p[0], p[1]); }
        { const float4* p = (const float4*)(gRow + k0); *(short8*)&Bg[row][seg * 8] = cvt8(p[0], p[1]); }
        { const float4* p = (const float4*)(uRow + k0); *(short8*)&Bu[row][seg * 8] = cvt8(p[0], p[1]); }
        __syncthreads();
        short8 a0 = *(const short8*)&As[wm + lr][lk];
        short8 a1 = *(const short8*)&As[wm + 16 + lr][lk];
        short8 g0 = *(const short8*)&Bg[wn + lr][lk];
        short8 g1 = *(const short8*)&Bg[wn + 16 + lr][lk];
        short8 u0 = *(const short8*)&Bu[wn + lr][lk];
        short8 u1 = *(const short8*)&Bu[wn + 16 + lr][lk];
        accg[0][0] = __builtin_amdgcn_mfma_f32_16x16x32_bf16(a0, g0, accg[0][0], 0, 0, 0);
        accg[0][1] = __builtin_amdgcn_mfma_f32_16x16x32_bf16(a0, g1, accg[0][1], 0, 0, 0);
        accg[1][0] = __builtin_amdgcn_mfma_f32_16x16x32_bf16(a1, g0, accg[1][0], 0, 0, 0);
        accg[1][1] = __builtin_amdgcn_mfma_f32_16x16x32_bf16(a1, g1, accg[1][1], 0, 0, 0);
        accu[0][0] = __builtin_amdgcn_mfma_f32_16x16x32_bf16(a0, u0, accu[0][0], 0, 0, 0);
        accu[0][1] = __builtin_amdgcn_mfma_f32_16x16x32_bf16(a0, u1, accu[0][1], 0, 0, 0);
        accu[1][0] = __builtin_amdgcn_mfma_f32_16x16x32_bf16(a1, u0, accu[1][0], 0, 0, 0);
        accu[1][1] = __builtin_amdgcn_mfma_f32_16x16x32_bf16(a1, u1, accu[1][1], 0, 0, 0);
        __syncthreads();
    }
#pragma unroll
    for (int mi = 0; mi < 2; mi++)
#pragma unroll
        for (int ni = 0; ni < 2; ni++)
#pragma unroll
            for (int r = 0; r < 4; r++) {
                int m = wm + mi * 16 + (lane >> 4) * 4 + r;
                int n = wn + ni * 16 + lr;
                float g = accg[mi][ni][r];
                float u = accu[mi][ni][r];
                Hs[m][n] = f2bf((g / (1.f + __expf(-g))) * u * Wl[m]);
            }
    __syncthreads();
    unsigned short* dst = H + (size_t)(slot0 + row) * FDIM + f0 + seg * 16;
    *(short8*)dst       = *(const short8*)&Hs[row][seg * 16];
    *(short8*)(dst + 8) = *(const short8*)&Hs[row][seg * 16 + 8];
}

__global__ __launch_bounds__(256) void expertB64_k(
    const unsigned short* __restrict__ H, const float* __restrict__ dw,
    const int* __restrict__ wsi, float* __restrict__ out)
{
    __shared__ unsigned short As[TMO][40];
    __shared__ unsigned short Bd[TMO][40];
    __shared__ int Ts[TMO];

    int tile = blockIdx.y;
    if (tile >= wsi[WS_NTILES]) return;
    int e     = wsi[WS_TILE_E + tile];
    int slot0 = wsi[WS_TILE_B + tile];
    int d0    = blockIdx.x * 64;
    int tid   = threadIdx.x;

    if (tid < TMO) Ts[tid] = wsi[WS_SLOTT + slot0 + tid];
    __syncthreads();

    int row = tid >> 2, seg = tid & 3;
    const unsigned short* aRow = H + (size_t)(slot0 + row) * FDIM + seg * 8;
    const float* dRow = dw + ((size_t)e * DIM + d0 + row) * FDIM + seg * 8;

    int wid = tid >> 6, lane = tid & 63;
    int wm = (wid >> 1) * 32, wn = (wid & 1) * 32;
    int lr = lane & 15, lk = (lane >> 4) * 8;

    f32x4 acc[2][2];
#pragma unroll
    for (int i = 0; i < 2; i++)
#pragma unroll
        for (int j = 0; j < 2; j++) acc[i][j] = (f32x4)0.f;

    for (int k0 = 0; k0 < FDIM; k0 += BK) {
        *(short8*)&As[row][seg * 8] = *(const short8*)(aRow + k0);
        { const float4* p = (const float4*)(dRow + k0); *(short8*)&Bd[row][seg * 8] = cvt8(p[0], p[1]); }
        __syncthreads();
        short8 a0 = *(const short8*)&As[wm + lr][lk];
        short8 a1 = *(const short8*)&As[wm + 16 + lr][lk];
        short8 b0 = *(const short8*)&Bd[wn + lr][lk];
        short8 b1 = *(const short8*)&Bd[wn + 16 + lr][lk];
        acc[0][0] = __builtin_amdgcn_mfma_f32_16x16x32_bf16(a0, b0, acc[0][0], 0, 0, 0);
        acc[0][1] = __builtin_amdgcn_mfma_f32_16x16x32_bf16(a0, b1, acc[0][1], 0, 0, 0);
        acc[1][0] = __builtin_amdgcn_mfma_f32_16x16x32_bf16(a1, b0, acc[1][0], 0, 0, 0);
        acc[1][1] = __builtin_amdgcn_mfma_f32_16x16x32_bf16(a1, b1, acc[1][1], 0, 0, 0);
        __syncthreads();
    }
#pragma unroll
    for (int mi = 0; mi < 2; mi++)
#pragma unroll
        for (int ni = 0; ni < 2; ni++)
#pragma unroll
            for (int r = 0; r < 4; r++) {
                int m = wm + mi * 16 + (lane >> 4) * 4 + r;
                int n = d0 + wn + ni * 16 + lr;
                atomicAdd(&out[(size_t)Ts[m] * DIM + n], acc[mi][ni][r]);
            }
}

extern "C" void kernel_launch(void* const* d_in, const int* in_sizes, int n_in,
                              void* d_out, int out_size, void* d_ws, size_t ws_size,
                              hipStream_t stream) {
    const float* x  = (const float*)d_in[0];
    const float* rw = (const float*)d_in[1];
    const float* gw = (const float*)d_in[2];
    const float* uw = (const float*)d_in[3];
    const float* dw = (const float*)d_in[4];
    float* out    = (float*)d_out;
    float* logits = out + (size_t)NTOK * DIM;
    int*   wsi = (int*)d_ws;
    float* wsf = (float*)d_ws;

    hipMemsetAsync(d_ws, 0, 4096, stream);

    if (ws_size >= WS_NEED) {
        unsigned short* xbf = (unsigned short*)((char*)d_ws + B_XBF);
        unsigned short* H   = (unsigned short*)((char*)d_ws + B_H);
        unsigned short* gbf = (unsigned short*)((char*)d_ws + B_GBF);
        unsigned short* ubf = (unsigned short*)((char*)d_ws + B_UBF);
        unsigned short* dbf = (unsigned short*)((char*)d_ws + B_DBF);
        float*          Osl = (float*)((char*)d_ws + B_OSL);
        const int nw8 = NEXP * FDIM * DIM / 8;   // 3,145,728
        router_k<<<NTOK / 4, 256, 0, stream>>>(x, rw, logits, wsi, wsf, xbf);
        cvtw_k<<<dim3(nw8 / 256, 3), 256, 0, stream>>>(gw, uw, dw, gbf, ubf, dbf, nw8);
        scan_k   <<<1, 256, 0, stream>>>(wsi, wsf, 1, SLOTW_NEW, MAX_SLOTS_N);
        scatter_k<<<NTOK / 256, 256, 0, stream>>>(wsi, wsf, SLOTW_NEW);
        expertA_k<<<dim3(FDIM / TNA, MAX_TILES_N), 256, 0, stream>>>(xbf, gbf, ubf, wsi, wsf, H);
        expertB_k<<<dim3(DIM / TNB, MAX_TILES_N), 256, 0, stream>>>(H, dbf, wsi, Osl);
        combine_k<<<NTOK * DIM / 4 / 256, 256, 0, stream>>>(Osl, wsi, out);
    } else {
        unsigned short* H = (unsigned short*)((char*)d_ws + B_HOLD);
        hipMemsetAsync(d_out, 0, (size_t)NTOK * DIM * sizeof(float), stream);
        router_k<<<NTOK / 4, 256, 0, stream>>>(x, rw, logits, wsi, wsf, nullptr);
        scan_k   <<<1, 256, 0, stream>>>(wsi, wsf, 0, SLOTW_OLD, MAX_SLOTS_O);
        scatter_k<<<NTOK / 256, 256, 0, stream>>>(wsi, wsf, SLOTW_OLD);
        expertA64_k<<<dim3(FDIM / 64, MAX_TILES), 256, 0, stream>>>(x, gw, uw, wsi, wsf, H);
        expertB64_k<<<dim3(DIM / 64, MAX_TILES), 256, 0, stream>>>(H, dw, wsi, out);
    }
}